// Round 12
// baseline (136.798 us; speedup 1.0000x reference)
//
#include <hip/hip_runtime.h>
#include <math.h>

constexpr int B_   = 4096;
constexpr int C_   = 100;
constexpr int TWOB = 8192;
constexpr int NJ   = 8292;
constexpr int NJP  = 8320;          // padded cols (520 quanta of 16)
constexpr float LOG2E10 = 14.4269504089f;   // 10 * log2(e)
constexpr float LN2     = 0.6931471805599453f;

typedef __attribute__((ext_vector_type(8))) short short8;
typedef __attribute__((ext_vector_type(4))) float f32x4;

// ---------------- ws layout (bytes) ----------------
// 0       : int    cnt[128]             512
// 512     : float  Epart[16*8192]    524288 -> 524800   (per-strip partials, non-atomic)
// 524800  : float  Spart[16*8192]    524288 -> 1049088
// 1049088 : float4 tbl[8320]         133120 -> 1182208  (.x=jt bits, .y=r0, .z=r1)
// 1182208 : int    tgtAll[8320]       33280 -> 1215488
// 1215488 : ushort fbB[8320*128]    2129920 -> 3345408  (unscaled bf16)
// 3345408 : ushort fbA[8192*128]    2097152 -> 5442560  (bf16 of feat*14.4269504)

__device__ __forceinline__ const float* feat_row(const float* __restrict__ centers,
                                                 const float* __restrict__ features,
                                                 int idx) {
  if (idx < B_)   return features + (size_t)idx * 256;
  if (idx < TWOB) return features + (size_t)(idx - B_) * 256 + 128;
  return centers + (size_t)(idx - TWOB) * 128;
}

__device__ __forceinline__ unsigned short f2bf(float x) {
  unsigned int u = __float_as_uint(x);
  unsigned int r = (u + 0x7FFFu + ((u >> 16) & 1u)) >> 16;   // RNE
  return (unsigned short)r;
}

__device__ __forceinline__ float bf2f(short s) {
  return __uint_as_float(((unsigned int)(unsigned short)s) << 16);
}

// single block: LDS histogram for class counts + targets table + zero out[0]
__global__ __launch_bounds__(1024)
void tgt_count_kernel(const int* __restrict__ targets, int* __restrict__ cnt,
                      int* __restrict__ tgtAll, float* __restrict__ out) {
  __shared__ int h[128];
  int t = threadIdx.x;
  if (t < 128) h[t] = 0;
  if (t == 1023) out[0] = 0.f;
  __syncthreads();
  for (int i = t; i < NJP; i += 1024) {
    int jt = (i < B_) ? targets[i]
           : (i < TWOB ? targets[i - B_] : (i < NJ ? i - TWOB : -9));
    tgtAll[i] = jt;
    if (i < B_) atomicAdd(&h[jt], 1);
  }
  __syncthreads();
  if (t < 128) cnt[t] = h[t];
}

// bf16 conversions + per-column tables
__global__ __launch_bounds__(256)
void prep_kernel(const float* __restrict__ centers, const float* __restrict__ features,
                 const int* __restrict__ tgtAll, const int* __restrict__ cnt,
                 unsigned short* __restrict__ fbB, unsigned short* __restrict__ fbA,
                 float4* __restrict__ tbl) {
  int gidx = blockIdx.x * 256 + threadIdx.x;      // NJP*32 items
  if (gidx >= NJP * 32) return;
  int row = gidx >> 5;
  int q   = gidx & 31;                            // float4 index within row
  float4 v = make_float4(0.f, 0.f, 0.f, 0.f);
  if (row < NJ) v = *(const float4*)(feat_row(centers, features, row) + q * 4);
  ushort4 o;
  o.x = f2bf(v.x); o.y = f2bf(v.y); o.z = f2bf(v.z); o.w = f2bf(v.w);
  *(ushort4*)&fbB[(size_t)row * 128 + q * 4] = o;
  if (row < TWOB) {
    ushort4 a;
    a.x = f2bf(v.x * LOG2E10); a.y = f2bf(v.y * LOG2E10);
    a.z = f2bf(v.z * LOG2E10); a.w = f2bf(v.w * LOG2E10);
    *(ushort4*)&fbA[(size_t)row * 128 + q * 4] = a;
  }
  if (q == 0) {
    int jt = tgtAll[row];
    float r0 = 0.f, r1 = 0.f;
    if (jt >= 0) {
      float b = (float)(2 * cnt[jt] + 1);
      r0 = 1.f / b;
      r1 = 1.f / (b - 1.f);     // = 1/(2*cnt); inf only if cnt==0, never selected
    }
    tbl[row] = make_float4(__int_as_float(jt), r0, r1, 0.f);
  }
}

// Wave-independent 32-row x 16-col MFMA quanta, no LDS, no barriers, no atomics.
// Grid 1024 blocks: id = strip(16) + 16*isuper(64); id%8 = strip%8 -> 2 strips/XCD.
// waves_per_eu(4,4): exactly 4 waves/EU -> 128 VGPR budget; live set ~100.
// R11 lesson: compiler SANK the loop-invariant af/ti loads into the loop
// (VGPR=52, 2.6x L2 traffic, latency-bound). The asm "+v" fences below make
// those values opaque so they MUST stay in registers across the loop.
__global__ __launch_bounds__(256) __attribute__((amdgpu_waves_per_eu(4, 4)))
void bal_mfma(const unsigned short* __restrict__ fbA, const unsigned short* __restrict__ fbB,
              const float4* __restrict__ tbl,
              float* __restrict__ Epart, float* __restrict__ Spart) {
  const int t     = threadIdx.x;
  const int lane  = t & 63;
  const int w     = t >> 6;
  const int id    = blockIdx.x;
  const int strip = id & 15;
  const int isup  = id >> 4;
  const int rbase = isup * 128 + w * 32;
  const int lr    = lane & 15;
  const int lh    = lane >> 4;

  // 520 quanta of 16 cols over 16 strips: strips 0..7 get 33, 8..15 get 32
  const int q0 = strip * 32 + (strip < 8 ? strip : 8);
  const int q1 = q0 + 32 + (strip < 8 ? 1 : 0);

  // ---- A fragments (scaled copy), held for the whole strip: 32 VGPR ----
  short8 af[4][2];                  // [ks][m]
  #pragma unroll
  for (int ks = 0; ks < 4; ++ks)
    #pragma unroll
    for (int m = 0; m < 2; ++m)
      af[ks][m] = *(const short8*)&fbA[(size_t)(rbase + m * 16 + lr) * 128 + (ks * 4 + lh) * 8];

  int ti[2][4];
  #pragma unroll
  for (int m = 0; m < 2; ++m)
    #pragma unroll
    for (int g = 0; g < 4; ++g)
      ti[m][g] = __float_as_int(tbl[rbase + m * 16 + lh * 4 + g].x);

  // register fence: value may have been "modified" -> no remat, stays in VGPRs
  #pragma unroll
  for (int ks = 0; ks < 4; ++ks)
    #pragma unroll
    for (int m = 0; m < 2; ++m)
      asm volatile("" : "+v"(af[ks][m]));
  #pragma unroll
  for (int m = 0; m < 2; ++m)
    #pragma unroll
    for (int g = 0; g < 4; ++g)
      asm volatile("" : "+v"(ti[m][g]));

  float ep[2][4], ma[2][4];
  #pragma unroll
  for (int m = 0; m < 2; ++m)
    #pragma unroll
    for (int g = 0; g < 4; ++g) { ep[m][g] = 0.f; ma[m][g] = 0.f; }

  for (int jq = q0; jq < q1; ++jq) {
    const int jb = jq * 16;
    // ---- load B quantum (16 rows x 128 dims) + column table ----
    float4 tb = tbl[jb + lr];
    short8 b[4];
    #pragma unroll
    for (int ks = 0; ks < 4; ++ks)
      b[ks] = *(const short8*)&fbB[(size_t)(jb + lr) * 128 + (ks * 4 + lh) * 8];

    // ---- MFMA ----
    f32x4 acc[2];
    #pragma unroll
    for (int m = 0; m < 2; ++m) acc[m] = (f32x4){0.f, 0.f, 0.f, 0.f};
    #pragma unroll
    for (int ks = 0; ks < 4; ++ks)
      #pragma unroll
      for (int m = 0; m < 2; ++m)
        acc[m] = __builtin_amdgcn_mfma_f32_16x16x32_bf16(af[ks][m], b[ks], acc[m], 0, 0, 0);

    // ---- fused epilogue ----
    const int   jtq = __float_as_int(tb.x);
    const float r0q = tb.y, r1q = tb.z;
    if ((unsigned)(jb - rbase) < 32u) {
      // quantum contains this wave's diagonal elements
      #pragma unroll
      for (int m = 0; m < 2; ++m)
        #pragma unroll
        for (int g = 0; g < 4; ++g) {
          float a = acc[m][g];
          float e = __builtin_amdgcn_exp2f(a);       // exp(10*dot)
          bool eq   = (ti[m][g] == jtq);
          bool diag = (jb + lr) == (rbase + m * 16 + lh * 4 + g);
          float r = diag ? 0.f : (eq ? r1q : r0q);
          ep[m][g] = fmaf(e, r, ep[m][g]);
          ma[m][g] += (eq && !diag) ? a : 0.f;
        }
    } else {
      #pragma unroll
      for (int m = 0; m < 2; ++m)
        #pragma unroll
        for (int g = 0; g < 4; ++g) {
          float a = acc[m][g];
          float e = __builtin_amdgcn_exp2f(a);
          bool eq = (ti[m][g] == jtq);
          ep[m][g] = fmaf(e, eq ? r1q : r0q, ep[m][g]);
          ma[m][g] += eq ? a : 0.f;
        }
    }
  }

  // ---- reduce over the 16 column-lanes; exclusive non-atomic stores ----
  #pragma unroll
  for (int mk = 1; mk <= 8; mk <<= 1)
    #pragma unroll
    for (int m = 0; m < 2; ++m)
      #pragma unroll
      for (int g = 0; g < 4; ++g) {
        ep[m][g] += __shfl_xor(ep[m][g], mk, 64);
        ma[m][g] += __shfl_xor(ma[m][g], mk, 64);
      }
  if (lr == 0) {
    #pragma unroll
    for (int m = 0; m < 2; ++m)
      #pragma unroll
      for (int g = 0; g < 4; ++g) {
        int i = rbase + m * 16 + lh * 4 + g;
        Epart[strip * TWOB + i] = ep[m][g];
        Spart[strip * TWOB + i] = ma[m][g];
      }
  }
}

// 32 blocks x 256: one row/thread, coalesced partial sums, atomic into out.
__global__ __launch_bounds__(256)
void bal_final(const float4* __restrict__ tbl,
               const float* __restrict__ Epart, const float* __restrict__ Spart,
               float* __restrict__ out) {
  int t   = threadIdx.x;
  int row = blockIdx.x * 256 + t;
  float E = 0.f, S = 0.f;
  #pragma unroll
  for (int s = 0; s < 16; ++s) {
    E += Epart[s * TWOB + row];
    S += Spart[s * TWOB + row];
  }
  float r1 = tbl[row].z;                   // 1/(2*cnt[t_i])
  float local = LN2 * S * r1 - logf(E);    // mean_log_prob_pos for this row
  #pragma unroll
  for (int mk = 1; mk < 64; mk <<= 1) local += __shfl_xor(local, mk, 64);
  __shared__ float red[4];
  if ((t & 63) == 0) red[t >> 6] = local;
  __syncthreads();
  if (t == 0)
    atomicAdd(out, -(red[0] + red[1] + red[2] + red[3]) / (float)TWOB);
}

extern "C" void kernel_launch(void* const* d_in, const int* in_sizes, int n_in,
                              void* d_out, int out_size, void* d_ws, size_t ws_size,
                              hipStream_t stream) {
  const float* centers  = (const float*)d_in[0];
  const float* features = (const float*)d_in[1];
  const int*   targets  = (const int*)d_in[2];

  char* ws = (char*)d_ws;
  int*            cnt    = (int*)ws;
  float*          Epart  = (float*)(ws + 512);
  float*          Spart  = (float*)(ws + 524800);
  float4*         tbl    = (float4*)(ws + 1049088);
  int*            tgtAll = (int*)(ws + 1182208);
  unsigned short* fbB    = (unsigned short*)(ws + 1215488);
  unsigned short* fbA    = (unsigned short*)(ws + 3345408);
  float* out = (float*)d_out;

  tgt_count_kernel<<<1, 1024, 0, stream>>>(targets, cnt, tgtAll, out);
  prep_kernel<<<(NJP * 32 + 255) / 256, 256, 0, stream>>>(centers, features, tgtAll, cnt,
                                                          fbB, fbA, tbl);
  bal_mfma<<<1024, 256, 0, stream>>>(fbA, fbB, tbl, Epart, Spart);
  bal_final<<<TWOB / 256, 256, 0, stream>>>(tbl, Epart, Spart, out);
}

// Round 13
// 136.020 us; speedup vs baseline: 1.0057x; 1.0057x over previous
//
#include <hip/hip_runtime.h>
#include <math.h>

constexpr int B_   = 4096;
constexpr int C_   = 100;
constexpr int TWOB = 8192;
constexpr int NJ   = 8292;
constexpr int NJP  = 8320;          // padded cols (520 quanta of 16)
constexpr float LOG2E10 = 14.4269504089f;   // 10 * log2(e)
constexpr float LN2     = 0.6931471805599453f;

typedef __attribute__((ext_vector_type(8))) short short8;
typedef __attribute__((ext_vector_type(4))) float f32x4;

// ---------------- ws layout (bytes) ----------------
// 0       : int    cnt[128]             512
// 512     : float  Epart[16*8192]    524288 -> 524800   (per-strip partials, non-atomic)
// 524800  : float  Spart[16*8192]    524288 -> 1049088
// 1049088 : float4 tbl[8320]         133120 -> 1182208  (.x=jt bits, .y=r0, .z=r1)
// 1182208 : int    tgtAll[8320]       33280 -> 1215488
// 1215488 : ushort fbB[8320*128]    2129920 -> 3345408  (unscaled bf16)
// 3345408 : ushort fbA[8192*128]    2097152 -> 5442560  (bf16 of feat*14.4269504)

__device__ __forceinline__ const float* feat_row(const float* __restrict__ centers,
                                                 const float* __restrict__ features,
                                                 int idx) {
  if (idx < B_)   return features + (size_t)idx * 256;
  if (idx < TWOB) return features + (size_t)(idx - B_) * 256 + 128;
  return centers + (size_t)(idx - TWOB) * 128;
}

__device__ __forceinline__ unsigned short f2bf(float x) {
  unsigned int u = __float_as_uint(x);
  unsigned int r = (u + 0x7FFFu + ((u >> 16) & 1u)) >> 16;   // RNE
  return (unsigned short)r;
}

__device__ __forceinline__ float bf2f(short s) {
  return __uint_as_float(((unsigned int)(unsigned short)s) << 16);
}

// single block: LDS histogram for class counts + targets table + zero out[0]
__global__ __launch_bounds__(1024)
void tgt_count_kernel(const int* __restrict__ targets, int* __restrict__ cnt,
                      int* __restrict__ tgtAll, float* __restrict__ out) {
  __shared__ int h[128];
  int t = threadIdx.x;
  if (t < 128) h[t] = 0;
  if (t == 1023) out[0] = 0.f;
  __syncthreads();
  for (int i = t; i < NJP; i += 1024) {
    int jt = (i < B_) ? targets[i]
           : (i < TWOB ? targets[i - B_] : (i < NJ ? i - TWOB : -9));
    tgtAll[i] = jt;
    if (i < B_) atomicAdd(&h[jt], 1);
  }
  __syncthreads();
  if (t < 128) cnt[t] = h[t];
}

// bf16 conversions + per-column tables
__global__ __launch_bounds__(256)
void prep_kernel(const float* __restrict__ centers, const float* __restrict__ features,
                 const int* __restrict__ tgtAll, const int* __restrict__ cnt,
                 unsigned short* __restrict__ fbB, unsigned short* __restrict__ fbA,
                 float4* __restrict__ tbl) {
  int gidx = blockIdx.x * 256 + threadIdx.x;      // NJP*32 items
  if (gidx >= NJP * 32) return;
  int row = gidx >> 5;
  int q   = gidx & 31;                            // float4 index within row
  float4 v = make_float4(0.f, 0.f, 0.f, 0.f);
  if (row < NJ) v = *(const float4*)(feat_row(centers, features, row) + q * 4);
  ushort4 o;
  o.x = f2bf(v.x); o.y = f2bf(v.y); o.z = f2bf(v.z); o.w = f2bf(v.w);
  *(ushort4*)&fbB[(size_t)row * 128 + q * 4] = o;
  if (row < TWOB) {
    ushort4 a;
    a.x = f2bf(v.x * LOG2E10); a.y = f2bf(v.y * LOG2E10);
    a.z = f2bf(v.z * LOG2E10); a.w = f2bf(v.w * LOG2E10);
    *(ushort4*)&fbA[(size_t)row * 128 + q * 4] = a;
  }
  if (q == 0) {
    int jt = tgtAll[row];
    float r0 = 0.f, r1 = 0.f;
    if (jt >= 0) {
      float b = (float)(2 * cnt[jt] + 1);
      r0 = 1.f / b;
      r1 = 1.f / (b - 1.f);     // = 1/(2*cnt); inf only if cnt==0, never selected
    }
    tbl[row] = make_float4(__int_as_float(jt), r0, r1, 0.f);
  }
}

// Wave-independent 32-row x 16-col MFMA quanta, no LDS, no barriers, no atomics.
// Grid 1024 blocks: id = strip(16) + 16*isuper(64); id%8 = strip%8 -> 2 strips/XCD.
// R11/R12 lesson: clang runtime-unrolls the quantum loop, register pressure
// spikes, and the allocator sinks the "loop-invariant" af/ti loads into every
// body (VGPR=52, ~5280 cyc/iter of serialized L2 reloads). Fix: (1) disable
// unrolling of the jq loop; (2) make af/ti LOOP-CARRIED opaque values via
// per-iteration asm fences so the loads cannot be sunk.
__global__ __launch_bounds__(256) __attribute__((amdgpu_waves_per_eu(4, 4)))
void bal_mfma(const unsigned short* __restrict__ fbA, const unsigned short* __restrict__ fbB,
              const float4* __restrict__ tbl,
              float* __restrict__ Epart, float* __restrict__ Spart) {
  const int t     = threadIdx.x;
  const int lane  = t & 63;
  const int w     = t >> 6;
  const int id    = blockIdx.x;
  const int strip = id & 15;
  const int isup  = id >> 4;
  const int rbase = isup * 128 + w * 32;
  const int lr    = lane & 15;
  const int lh    = lane >> 4;

  // 520 quanta of 16 cols over 16 strips: strips 0..7 get 33, 8..15 get 32
  const int q0 = strip * 32 + (strip < 8 ? strip : 8);
  const int q1 = q0 + 32 + (strip < 8 ? 1 : 0);

  // ---- A fragments (scaled copy), held for the whole strip: 32 VGPR ----
  short8 af[4][2];                  // [ks][m]
  #pragma unroll
  for (int ks = 0; ks < 4; ++ks)
    #pragma unroll
    for (int m = 0; m < 2; ++m)
      af[ks][m] = *(const short8*)&fbA[(size_t)(rbase + m * 16 + lr) * 128 + (ks * 4 + lh) * 8];

  int ti[2][4];
  #pragma unroll
  for (int m = 0; m < 2; ++m)
    #pragma unroll
    for (int g = 0; g < 4; ++g)
      ti[m][g] = __float_as_int(tbl[rbase + m * 16 + lh * 4 + g].x);

  float ep[2][4], ma[2][4];
  #pragma unroll
  for (int m = 0; m < 2; ++m)
    #pragma unroll
    for (int g = 0; g < 4; ++g) { ep[m][g] = 0.f; ma[m][g] = 0.f; }

  #pragma clang loop unroll(disable)
  for (int jq = q0; jq < q1; ++jq) {
    // loop-carried opaque fence: af/ti MUST live in registers across iterations
    #pragma unroll
    for (int ks = 0; ks < 4; ++ks)
      #pragma unroll
      for (int m = 0; m < 2; ++m)
        asm volatile("" : "+v"(af[ks][m]));
    #pragma unroll
    for (int m = 0; m < 2; ++m)
      #pragma unroll
      for (int g = 0; g < 4; ++g)
        asm volatile("" : "+v"(ti[m][g]));

    const int jb = jq * 16;
    // ---- load B quantum (16 rows x 128 dims) + column table ----
    float4 tb = tbl[jb + lr];
    short8 b[4];
    #pragma unroll
    for (int ks = 0; ks < 4; ++ks)
      b[ks] = *(const short8*)&fbB[(size_t)(jb + lr) * 128 + (ks * 4 + lh) * 8];

    // ---- MFMA ----
    f32x4 acc[2];
    #pragma unroll
    for (int m = 0; m < 2; ++m) acc[m] = (f32x4){0.f, 0.f, 0.f, 0.f};
    #pragma unroll
    for (int ks = 0; ks < 4; ++ks)
      #pragma unroll
      for (int m = 0; m < 2; ++m)
        acc[m] = __builtin_amdgcn_mfma_f32_16x16x32_bf16(af[ks][m], b[ks], acc[m], 0, 0, 0);

    // ---- fused epilogue ----
    const int   jtq = __float_as_int(tb.x);
    const float r0q = tb.y, r1q = tb.z;
    if ((unsigned)(jb - rbase) < 32u) {
      // quantum contains this wave's diagonal elements
      #pragma unroll
      for (int m = 0; m < 2; ++m)
        #pragma unroll
        for (int g = 0; g < 4; ++g) {
          float a = acc[m][g];
          float e = __builtin_amdgcn_exp2f(a);       // exp(10*dot)
          bool eq   = (ti[m][g] == jtq);
          bool diag = (jb + lr) == (rbase + m * 16 + lh * 4 + g);
          float r = diag ? 0.f : (eq ? r1q : r0q);
          ep[m][g] = fmaf(e, r, ep[m][g]);
          ma[m][g] += (eq && !diag) ? a : 0.f;
        }
    } else {
      #pragma unroll
      for (int m = 0; m < 2; ++m)
        #pragma unroll
        for (int g = 0; g < 4; ++g) {
          float a = acc[m][g];
          float e = __builtin_amdgcn_exp2f(a);
          bool eq = (ti[m][g] == jtq);
          ep[m][g] = fmaf(e, eq ? r1q : r0q, ep[m][g]);
          ma[m][g] += eq ? a : 0.f;
        }
    }
  }

  // ---- reduce over the 16 column-lanes; exclusive non-atomic stores ----
  #pragma unroll
  for (int mk = 1; mk <= 8; mk <<= 1)
    #pragma unroll
    for (int m = 0; m < 2; ++m)
      #pragma unroll
      for (int g = 0; g < 4; ++g) {
        ep[m][g] += __shfl_xor(ep[m][g], mk, 64);
        ma[m][g] += __shfl_xor(ma[m][g], mk, 64);
      }
  if (lr == 0) {
    #pragma unroll
    for (int m = 0; m < 2; ++m)
      #pragma unroll
      for (int g = 0; g < 4; ++g) {
        int i = rbase + m * 16 + lh * 4 + g;
        Epart[strip * TWOB + i] = ep[m][g];
        Spart[strip * TWOB + i] = ma[m][g];
      }
  }
}

// 32 blocks x 256: one row/thread, coalesced partial sums, atomic into out.
__global__ __launch_bounds__(256)
void bal_final(const float4* __restrict__ tbl,
               const float* __restrict__ Epart, const float* __restrict__ Spart,
               float* __restrict__ out) {
  int t   = threadIdx.x;
  int row = blockIdx.x * 256 + t;
  float E = 0.f, S = 0.f;
  #pragma unroll
  for (int s = 0; s < 16; ++s) {
    E += Epart[s * TWOB + row];
    S += Spart[s * TWOB + row];
  }
  float r1 = tbl[row].z;                   // 1/(2*cnt[t_i])
  float local = LN2 * S * r1 - logf(E);    // mean_log_prob_pos for this row
  #pragma unroll
  for (int mk = 1; mk < 64; mk <<= 1) local += __shfl_xor(local, mk, 64);
  __shared__ float red[4];
  if ((t & 63) == 0) red[t >> 6] = local;
  __syncthreads();
  if (t == 0)
    atomicAdd(out, -(red[0] + red[1] + red[2] + red[3]) / (float)TWOB);
}

extern "C" void kernel_launch(void* const* d_in, const int* in_sizes, int n_in,
                              void* d_out, int out_size, void* d_ws, size_t ws_size,
                              hipStream_t stream) {
  const float* centers  = (const float*)d_in[0];
  const float* features = (const float*)d_in[1];
  const int*   targets  = (const int*)d_in[2];

  char* ws = (char*)d_ws;
  int*            cnt    = (int*)ws;
  float*          Epart  = (float*)(ws + 512);
  float*          Spart  = (float*)(ws + 524800);
  float4*         tbl    = (float4*)(ws + 1049088);
  int*            tgtAll = (int*)(ws + 1182208);
  unsigned short* fbB    = (unsigned short*)(ws + 1215488);
  unsigned short* fbA    = (unsigned short*)(ws + 3345408);
  float* out = (float*)d_out;

  tgt_count_kernel<<<1, 1024, 0, stream>>>(targets, cnt, tgtAll, out);
  prep_kernel<<<(NJP * 32 + 255) / 256, 256, 0, stream>>>(centers, features, tgtAll, cnt,
                                                          fbB, fbA, tbl);
  bal_mfma<<<1024, 256, 0, stream>>>(fbA, fbB, tbl, Epart, Spart);
  bal_final<<<TWOB / 256, 256, 0, stream>>>(tbl, Epart, Spart, out);
}